// Round 12
// baseline (45.115 us; speedup 1.0000x reference)
//
#include <hip/hip_runtime.h>
#include <math.h>

#define IMG_H 512
#define IMG_W 512
#define TW 128           // tile width (output cols per block)
#define TH 32            // tile height per march step
#define MROWS 36         // TH + 4 src rows
#define MARCH 4          // steps per block -> block covers 128 x 128

typedef float f32x4 __attribute__((ext_vector_type(4)));
typedef float f32x2 __attribute__((ext_vector_type(2)));

__device__ __forceinline__ int reflect101(int i, int n) {
    if (i < 0) i = -i;
    if (i >= n) i = 2 * n - 2 - i;
    return i;
}

// fire-and-forget 16B global->LDS DMA (no VGPR round-trip, cannot be sunk)
__device__ __forceinline__ void gl_lds16(const float* g, float* l) {
    __builtin_amdgcn_global_load_lds(
        (const __attribute__((address_space(1))) unsigned int*)g,
        (__attribute__((address_space(3))) unsigned int*)l, 16, 0, 0);
}

// ---- staging: main [36][128] f32 (1 KB covers 2 rows per wave-instr)
//      halo   [64][2][4] f32 (cols tx0-4..-1 side0, tx0+128..131 side1)
__device__ __forceinline__ void stage_tile(const float* __restrict__ ip, int ty, int tx0,
                                           float* mb, float* hb, int tid,
                                           int gx0, int gx1) {
    const int wv = tid >> 6;          // wave 0..3
    const int l = tid & 63;
    const int lrow = l >> 5;          // 0..1
    const int lcol = (l & 31) * 4;    // f32 col within row
    #pragma unroll
    for (int i = 0; i < 5; ++i) {
        int p = wv + 4 * i;           // row-pair index
        if (p < 18) {
            int gy = reflect101(ty + 2 * p + lrow - 2, IMG_H);
            gl_lds16(ip + (size_t)gy * IMG_W + tx0 + lcol, mb + 2 * p * TW);
        }
    }
    if (wv == 2) {                    // halo rows 0..31: lane l -> row l>>1, side l&1
        int gy = reflect101(ty + (l >> 1) - 2, IMG_H);
        gl_lds16(ip + (size_t)gy * IMG_W + ((l & 1) ? gx1 : gx0), hb);
    }
    if (wv == 3) {                    // halo rows 32..35 (lanes past row 35 write waste)
        int r = 32 + (l >> 1);
        int gy = reflect101(ty + (r > 35 ? 35 : r) - 2, IMG_H);
        gl_lds16(ip + (size_t)gy * IMG_W + ((l & 1) ? gx1 : gx0), hb + 32 * 8);
    }
}

// ---- compute: 4-wide x 4-tall strip per thread, quantize-on-read ------------
// LDS row read: granules ga/gb/gc (b128 each) + halo b64
#define LDR(k, M0, M1, M2, H) do {                                            \
    const char* rp_ = mbc + (lr0 + (k)) * (TW * 4);                           \
    M0 = *(const f32x4*)(rp_ + ga);                                           \
    M1 = *(const f32x4*)(rp_ + gb);                                           \
    M2 = *(const f32x4*)(rp_ + gc);                                           \
    H  = *(const f32x2*)(hbc + (lr0 + (k)) * 32 + hoff);                      \
} while (0)

// quantized src cols xo-2..xo+5 -> Q0..Q7. floor(v*255) exact (uniform [0,1) input).
// Edge lanes: L (cg==0) cols -2,-1 from halo (or in-tile reflect if le);
//             R (cg==31) cols +4,+5 from halo (or in-tile reflect if re).
#define QR(M0, M1, M2, H, Q) do {                                             \
    float a0_ = L ? (le ? M1.z : H.x) : M0.z;                                 \
    float a1_ = L ? (le ? M1.y : H.y) : M0.w;                                 \
    float a6_ = R ? (re ? M1.z : H.x) : M2.x;                                 \
    float a7_ = R ? (re ? M1.y : H.y) : M2.y;                                 \
    Q##0 = floorf(a0_ * 255.0f);                                              \
    Q##1 = floorf(a1_ * 255.0f);                                              \
    Q##2 = floorf(M1.x * 255.0f);                                             \
    Q##3 = floorf(M1.y * 255.0f);                                             \
    Q##4 = floorf(M1.z * 255.0f);                                             \
    Q##5 = floorf(M1.w * 255.0f);                                             \
    Q##6 = floorf(a6_ * 255.0f);                                              \
    Q##7 = floorf(a7_ * 255.0f);                                              \
} while (0)

#define EMK(E, QA, QB) do {                                                   \
    E##0 = QA##0 + QB##0; E##1 = QA##1 + QB##1; E##2 = QA##2 + QB##2;         \
    E##3 = QA##3 + QB##3; E##4 = QA##4 + QB##4; E##5 = QA##5 + QB##5;         \
    E##6 = QA##6 + QB##6; E##7 = QA##7 + QB##7;                               \
} while (0)

// blur cols xo-1..xo+4 (BL0..BL5). Sums <= 4080 exact; rintf == round-half-even.
#define BLM(BL, EA, EB) do {                                                  \
    float cs0 = EA##0 + EB##0, cs1 = EA##1 + EB##1, cs2 = EA##2 + EB##2;      \
    float cs3 = EA##3 + EB##3, cs4 = EA##4 + EB##4, cs5 = EA##5 + EB##5;      \
    float cs6 = EA##6 + EB##6, cs7 = EA##7 + EB##7;                           \
    float d0 = cs0 + cs1, d1 = cs1 + cs2, d2 = cs2 + cs3, d3 = cs3 + cs4;     \
    float d4 = cs4 + cs5, d5 = cs5 + cs6, d6 = cs6 + cs7;                     \
    BL##0 = rintf((d0 + d1) * 0.0625f);                                       \
    BL##1 = rintf((d1 + d2) * 0.0625f);                                       \
    BL##2 = rintf((d2 + d3) * 0.0625f);                                       \
    BL##3 = rintf((d3 + d4) * 0.0625f);                                       \
    BL##4 = rintf((d4 + d5) * 0.0625f);                                       \
    BL##5 = rintf((d5 + d6) * 0.0625f);                                       \
} while (0)

#define OUTR(BA, BB, BC, T) do {                                              \
    float u0 = BA##0 + BC##0, u1 = BA##1 + BC##1, u2 = BA##2 + BC##2;         \
    float u3 = BA##3 + BC##3, u4 = BA##4 + BC##4, u5 = BA##5 + BC##5;         \
    f32x4 o_; float h_;                                                       \
    h_ = fmaf(-4.0f, BB##1, u0 + u2); o_.x = fminf(2.0f * fabsf(h_), 255.0f); \
    h_ = fmaf(-4.0f, BB##2, u1 + u3); o_.y = fminf(2.0f * fabsf(h_), 255.0f); \
    h_ = fmaf(-4.0f, BB##3, u2 + u4); o_.z = fminf(2.0f * fabsf(h_), 255.0f); \
    h_ = fmaf(-4.0f, BB##4, u3 + u5); o_.w = fminf(2.0f * fabsf(h_), 255.0f); \
    *(f32x4*)&op[(size_t)(ty + 4 * rb + (T)) * IMG_W + xo] = o_;              \
} while (0)

__global__ __launch_bounds__(256, 4) void lap_fused(const float* __restrict__ in,
                                                    float* __restrict__ out) {
    __shared__ float s_main[2][MROWS][TW];    // 36864 B
    __shared__ float s_halo[2][64][2][4];     //  4096 B  (total 40960 -> 4 blocks/CU)

    const int img = blockIdx.z;
    const int tx0 = blockIdx.x * TW;
    const int ty0 = blockIdx.y * (MARCH * TH);
    const float* __restrict__ ip = in + (size_t)img * (IMG_H * IMG_W);
    float* __restrict__ op = out + (size_t)img * (IMG_H * IMG_W);
    const int tid = threadIdx.x;

    const bool le = (tx0 == 0);
    const bool re = (tx0 == IMG_W - TW);
    const int gx0 = le ? 0 : (tx0 - 4);               // left-halo f4 base (clamped)
    const int gx1 = re ? (IMG_W - 4) : (tx0 + TW);    // right-halo f4 base (clamped)

    // compute mapping
    const int cg = tid & 31;
    const int rb = tid >> 5;
    const int xo = tx0 + 4 * cg;
    const int lr0 = 4 * rb;
    const bool L = (cg == 0), R = (cg == 31);
    const int ga = 16 * (L ? 0 : (cg - 1));
    const int gb = 16 * cg;
    const int gc = 16 * (R ? 31 : (cg + 1));
    const int hoff = R ? 16 : 8;                      // halo b64: side0 elems 2,3 / side1 elems 0,1

    stage_tile(ip, ty0, tx0, &s_main[0][0][0], &s_halo[0][0][0][0], tid, gx0, gx1);
    __syncthreads();

    #pragma unroll
    for (int t = 0; t < MARCH; ++t) {
        if (t + 1 < MARCH)
            stage_tile(ip, ty0 + (t + 1) * TH, tx0,
                       &s_main[(t + 1) & 1][0][0], &s_halo[(t + 1) & 1][0][0][0],
                       tid, gx0, gx1);   // fire-and-forget; lands under compute below

        const int ty = ty0 + t * TH;
        const char* mbc = (const char*)&s_main[t & 1][0][0];
        const char* hbc = (const char*)&s_halo[t & 1][0][0][0];

        f32x4 A0, A1, A2, B0, B1, B2;
        f32x2 Ha, Hb;
        float qA0, qA1, qA2, qA3, qA4, qA5, qA6, qA7;
        float qB0, qB1, qB2, qB3, qB4, qB5, qB6, qB7;
        float eA0, eA1, eA2, eA3, eA4, eA5, eA6, eA7;
        float eB0, eB1, eB2, eB3, eB4, eB5, eB6, eB7;
        float bP0, bP1, bP2, bP3, bP4, bP5;
        float bQ0, bQ1, bQ2, bQ3, bQ4, bQ5;
        float bR0, bR1, bR2, bR3, bR4, bR5;

        LDR(0, A0, A1, A2, Ha); LDR(1, B0, B1, B2, Hb);
        QR(A0, A1, A2, Ha, qA);  LDR(2, A0, A1, A2, Ha);
        QR(B0, B1, B2, Hb, qB);  EMK(eA, qA, qB);  LDR(3, B0, B1, B2, Hb);
        QR(A0, A1, A2, Ha, qA);  EMK(eB, qB, qA);  BLM(bP, eA, eB);  LDR(4, A0, A1, A2, Ha);
        QR(B0, B1, B2, Hb, qB);  EMK(eA, qA, qB);  BLM(bQ, eB, eA);  LDR(5, B0, B1, B2, Hb);
        QR(A0, A1, A2, Ha, qA);  EMK(eB, qB, qA);  BLM(bR, eA, eB);  OUTR(bP, bQ, bR, 0);
        LDR(6, A0, A1, A2, Ha);
        QR(B0, B1, B2, Hb, qB);  EMK(eA, qA, qB);  BLM(bP, eB, eA);  OUTR(bQ, bR, bP, 1);
        LDR(7, B0, B1, B2, Hb);
        QR(A0, A1, A2, Ha, qA);  EMK(eB, qB, qA);  BLM(bQ, eA, eB);  OUTR(bR, bP, bQ, 2);
        QR(B0, B1, B2, Hb, qB);  EMK(eA, qA, qB);  BLM(bR, eB, eA);  OUTR(bP, bQ, bR, 3);

        __syncthreads();   // drains staging vmcnt (auto) + guards buffer reuse
    }
}

extern "C" void kernel_launch(void* const* d_in, const int* in_sizes, int n_in,
                              void* d_out, int out_size, void* d_ws, size_t ws_size,
                              hipStream_t stream) {
    const float* x = (const float*)d_in[0];
    float* out = (float*)d_out;
    dim3 grid(IMG_W / TW, IMG_H / (MARCH * TH), 96);  // 4 x 4 x 96 = 1536 blocks
    dim3 block(256);
    lap_fused<<<grid, block, 0, stream>>>(x, out);
}

// Round 13
// 39.137 us; speedup vs baseline: 1.1527x; 1.1527x over previous
//
#include <hip/hip_runtime.h>
#include <math.h>

#define IMG_H 512
#define IMG_W 512
#define SW 256        // strip width per wave (f32 cols)
#define RING 8        // LDS row ring per wave

typedef float f32x4 __attribute__((ext_vector_type(4)));
typedef float f32x2 __attribute__((ext_vector_type(2)));

__device__ __forceinline__ int reflect101(int i, int n) {
    if (i < 0) i = -i;
    if (i >= n) i = 2 * n - 2 - i;
    return i;
}

// fire-and-forget 16B/lane global->LDS DMA; LDS dest = uniform base + lane*16
__device__ __forceinline__ void gl_lds16(const float* g, float* l) {
    __builtin_amdgcn_global_load_lds(
        (const __attribute__((address_space(1))) unsigned int*)g,
        (__attribute__((address_space(3))) unsigned int*)l, 16, 0, 0);
}

// Stage src row V (strip-local 0..35) into ring slot V&7: 1 main DMA + 1 halo DMA.
#define STAGE(V) do {                                                         \
    const int sl_ = (V) & 7;                                                  \
    const int gy_ = reflect101(ty0 + (V) - 2, IMG_H);                         \
    const float* rp_ = ip + (size_t)gy_ * IMG_W;                              \
    gl_lds16(rp_ + tx0 + 4 * l, mw + sl_ * SW);                               \
    if (l < 2) gl_lds16(rp_ + (l ? gx1 : gx0), hw + sl_ * 8);                 \
} while (0)

// Read one staged row: 3 b128 granules + halo b64 (per-lane cols xo-2..xo+5)
#define LDR(SLOT) do {                                                        \
    const float* rb_ = mw + (SLOT) * SW;                                      \
    M0 = *(const f32x4*)(rb_ + ga);                                           \
    M1 = *(const f32x4*)(rb_ + gb);                                           \
    M2 = *(const f32x4*)(rb_ + gc);                                           \
    H  = *(const f32x2*)(hw + (SLOT) * 8 + hoff);                             \
} while (0)

// Quantize 8 cols xo-2..xo+5. floor(v*255) exact for uniform[0,1) input.
// Lane 0 / lane 63 pull cols beyond the strip from halo (or in-tile reflect at edges).
#define QR(Q) do {                                                            \
    float a0_ = L ? (le ? M1.z : H.x) : M0.z;                                 \
    float a1_ = L ? (le ? M1.y : H.y) : M0.w;                                 \
    float a6_ = R ? (re ? M1.z : H.x) : M2.x;                                 \
    float a7_ = R ? (re ? M1.y : H.y) : M2.y;                                 \
    Q[0] = floorf(a0_ * 255.0f);  Q[1] = floorf(a1_ * 255.0f);                \
    Q[2] = floorf(M1.x * 255.0f); Q[3] = floorf(M1.y * 255.0f);               \
    Q[4] = floorf(M1.z * 255.0f); Q[5] = floorf(M1.w * 255.0f);               \
    Q[6] = floorf(a6_ * 255.0f);  Q[7] = floorf(a7_ * 255.0f);                \
} while (0)

#define EMK(E, QA, QB) do {                                                   \
    _Pragma("unroll") for (int j_ = 0; j_ < 8; ++j_) E[j_] = QA[j_] + QB[j_]; \
} while (0)

// 6-wide blur row from two 8-wide e-rows. Sums <=4080 exact; rintf == jnp.round.
#define BLM(BL, EA, EB) do {                                                  \
    float cs_[8], d_[7];                                                      \
    _Pragma("unroll") for (int j_ = 0; j_ < 8; ++j_) cs_[j_] = EA[j_] + EB[j_]; \
    _Pragma("unroll") for (int j_ = 0; j_ < 7; ++j_) d_[j_] = cs_[j_] + cs_[j_ + 1]; \
    _Pragma("unroll") for (int j_ = 0; j_ < 6; ++j_)                          \
        BL[j_] = rintf((d_[j_] + d_[j_ + 1]) * 0.0625f);                      \
} while (0)

// Laplacian + |.| + clip, 4 cols, one b128 store. Integer-exact.
#define OUTR(BA, BB, BC, T) do {                                              \
    float u_[6];                                                              \
    _Pragma("unroll") for (int j_ = 0; j_ < 6; ++j_) u_[j_] = BA[j_] + BC[j_]; \
    f32x4 o_; float h_;                                                       \
    h_ = fmaf(-4.0f, BB[1], u_[0] + u_[2]); o_.x = fminf(2.0f * fabsf(h_), 255.0f); \
    h_ = fmaf(-4.0f, BB[2], u_[1] + u_[3]); o_.y = fminf(2.0f * fabsf(h_), 255.0f); \
    h_ = fmaf(-4.0f, BB[3], u_[2] + u_[4]); o_.z = fminf(2.0f * fabsf(h_), 255.0f); \
    h_ = fmaf(-4.0f, BB[4], u_[3] + u_[5]); o_.w = fminf(2.0f * fabsf(h_), 255.0f); \
    *(f32x4*)&op[(size_t)(ty0 + (T)) * IMG_W + xo] = o_;                      \
} while (0)

__global__ __launch_bounds__(256) void lap_fused(const float* __restrict__ in,
                                                 float* __restrict__ out) {
    __shared__ float s_m[4][RING][SW];   // 32768 B: per-wave private row rings
    __shared__ float s_h[4][RING][8];    //  1024 B: per-wave halo rings

    const int tid = threadIdx.x;
    const int wv = tid >> 6;
    const int l = tid & 63;

    // wave-task: 96 imgs x 2 x-halves x 16 y-bands = 3072 waves, no barriers anywhere
    const int wg = blockIdx.x * 4 + wv;
    const int img = wg >> 5;
    const int t = wg & 31;
    const int xh = t >> 4;
    const int yb = t & 15;
    const int tx0 = xh * SW;
    const int ty0 = yb * 32;

    const float* __restrict__ ip = in + (size_t)img * (IMG_H * IMG_W);
    float* __restrict__ op = out + (size_t)img * (IMG_H * IMG_W);

    float* mw = &s_m[wv][0][0];
    float* hw = &s_h[wv][0][0];

    const bool le = (xh == 0);                 // strip at left image edge
    const bool re = (xh == 1);                 // strip at right image edge
    const int gx0 = le ? 0 : (tx0 - 4);        // left-halo granule base (clamped)
    const int gx1 = re ? (IMG_W - 4) : (tx0 + SW);

    const bool L = (l == 0), R = (l == 63);
    const int ga = L ? 0 : 4 * (l - 1);
    const int gb = 4 * l;
    const int gc = R ? 4 * 63 : 4 * (l + 1);
    const int hoff = R ? 4 : 2;                // halo b64: left elems 2,3 / right 4,5
    const int xo = tx0 + 4 * l;

    f32x4 M0, M1, M2; f32x2 H;
    float qq[2][8], el[2][8], bl[3][6];
    float e0t[8], e1t[8];

    // ---- prologue: stage rows 0..6 (14 DMA ops), then build state from rows 0..3
    #pragma unroll
    for (int s = 0; s < 7; ++s) STAGE(s);
    __builtin_amdgcn_sched_barrier(0);
    asm volatile("s_waitcnt vmcnt(6)" ::: "memory");   // rows 0..3 landed
    __builtin_amdgcn_sched_barrier(0);

    LDR(0); QR(qq[0]);                         // q0
    LDR(1); QR(qq[1]);                         // q1
    EMK(e0t, qq[0], qq[1]);                    // e(0)
    LDR(2); QR(qq[0]);                         // q2
    EMK(e1t, qq[1], qq[0]);                    // e(1)
    BLM(bl[2], e0t, e1t);                      // bl(-1)
    LDR(3); QR(qq[1]);                         // q3
    EMK(el[0], qq[0], qq[1]);                  // e(2)
    BLM(bl[0], e1t, el[0]);                    // bl(0)

    // ---- steady stream: 1 row staged + 1 row computed per iter; counted vmcnt only
    #pragma unroll
    for (int r = 0; r < 32; ++r) {
        if (r + 7 <= 35) STAGE(r + 7);
        __builtin_amdgcn_sched_barrier(0);     // pin stage above the wait
        // N = ops issued after stage(r+4): 2*(#stages after) + min(r,3) stores
        switch (r) {
            case 0:  asm volatile("s_waitcnt vmcnt(6)" ::: "memory"); break;
            case 1:  asm volatile("s_waitcnt vmcnt(7)" ::: "memory"); break;
            case 2:  asm volatile("s_waitcnt vmcnt(8)" ::: "memory"); break;
            case 29: asm volatile("s_waitcnt vmcnt(7)" ::: "memory"); break;
            case 30: asm volatile("s_waitcnt vmcnt(5)" ::: "memory"); break;
            case 31: asm volatile("s_waitcnt vmcnt(3)" ::: "memory"); break;
            default: asm volatile("s_waitcnt vmcnt(9)" ::: "memory"); break;
        }
        __builtin_amdgcn_sched_barrier(0);     // keep ds_reads below the wait (rule #18)

        LDR((r + 4) & 7);                      // src row r+4
        QR(qq[r & 1]);                         // q(r+4)
        EMK(el[(r + 1) & 1], qq[(r + 1) & 1], qq[r & 1]);   // e(r+3)
        BLM(bl[(r + 1) % 3], el[r & 1], el[(r + 1) & 1]);   // bl(r+1)
        OUTR(bl[(r + 2) % 3], bl[r % 3], bl[(r + 1) % 3], r);
    }
}

extern "C" void kernel_launch(void* const* d_in, const int* in_sizes, int n_in,
                              void* d_out, int out_size, void* d_ws, size_t ws_size,
                              hipStream_t stream) {
    const float* x = (const float*)d_in[0];
    float* out = (float*)d_out;
    dim3 grid(768);   // 3072 waves / 4 per block; 3 blocks per CU exact, tail-free
    dim3 block(256);
    lap_fused<<<grid, block, 0, stream>>>(x, out);
}